// Round 6
// baseline (68.814 us; speedup 1.0000x reference)
//
#include <hip/hip_runtime.h>

static constexpr int TI = 128;        // i-rows and j-cols per tile
static constexpr int NTHREADS = 256;  // 128 i-lanes x 2 j-halves

// d_ws layout: float s_part[nb], h_part[nb]. Every slot written unconditionally
// by its block each call -> no memset needed.
//
// Math notes:
//  - hinge term for unordered pair {i,j}: max(0, 1 - sgn(t_i-t_j)*(p_i-p_j))
//    is SYMMETRIC under i<->j swap, so relabeling/double-count+halve is exact.
//  - sg = med3(t_i - t_j, -1, 1) in {-1,0,+1} (targets are integer-valued);
//    term = max(0, |sg| - sg*(p_i-p_j)); equal targets give exactly 0.
//  - masked pair COUNT is pure combinatorics of the target histogram:
//    cnt = [n(n-1) - sum_v H_v(H_v-1)] / 2 — computed in finalize, not here.

__global__ __launch_bounds__(NTHREADS) void egl_pair_kernel(
    const float* __restrict__ pred, const float* __restrict__ targ, int n, int nT,
    float* __restrict__ ws_s, float* __restrict__ ws_h) {
  // Decode blockIdx.x -> upper-triangular tile pair (ti <= tj).
  int bidx = blockIdx.x;
  int ti = 0, rem = bidx;
  while (rem >= nT - ti) { rem -= (nT - ti); ++ti; }
  const int tj = ti + rem;

  __shared__ alignas(16) float2 sj[TI];  // (p_j, t_j)
  const int tid  = threadIdx.x;
  const int il   = tid & (TI - 1);
  const int half = tid >> 7;             // which 64-wide j-half this thread owns
  const int j0 = tj * TI;
  if (tid < TI) {
    int j = j0 + tid;
    float pj = (j < n) ? pred[j] : 0.0f;
    float tv = (j < n) ? targ[j] : 0.0f;   // pad target 0 with pad pred 0 -> sg vs pad may be nonzero
    if (j >= n) { pj = 0.0f; tv = -1e30f; } // sentinel: med3(t_i - (-1e30)) = 1, term = max(0,1-(p_i-0)) nonzero!
    sj[tid] = make_float2(pj, tv);
  }
  __syncthreads();

  const int i = ti * TI + il;
  const bool ivalid = (i < n);
  const float pi  = ivalid ? pred[i] : 0.0f;
  const float tiv = ivalid ? targ[i] : 0.0f;

  float s0 = 0.f, s1 = 0.f, s2 = 0.f, s3 = 0.f;
  float hub = 0.f;

  const int jcount = min(TI, n - j0);
  const float4* sj4 = (const float4*)sj;

  if (ivalid && ti == tj && half == 0) {  // Huber once per element i
    float d = pi - tiv;
    float ad = fabsf(d);
    hub = (ad < 1.0f) ? 0.5f * d * d : (ad - 0.5f);
  }

  // Uniform accumulation: every block sums ALL (i in tile_i) x (j in its half of
  // tile_j). Diagonal blocks double-count each unordered pair (and i==j gives 0),
  // fixed by a 0.5 scale on the block total.
  if (ivalid) {
    if (jcount == TI) {
      const int k0 = half * 32;  // float4 index base (each float4 = 2 j's)
#pragma unroll
      for (int k = 0; k < 32; k += 2) {
        float4 a = sj4[k0 + k];
        float4 b = sj4[k0 + k + 1];
        { float sg = __builtin_amdgcn_fmed3f(tiv - a.y, -1.f, 1.f);
          s0 += fmaxf(fmaf(-sg, pi - a.x, fabsf(sg)), 0.f); }
        { float sg = __builtin_amdgcn_fmed3f(tiv - a.w, -1.f, 1.f);
          s1 += fmaxf(fmaf(-sg, pi - a.z, fabsf(sg)), 0.f); }
        { float sg = __builtin_amdgcn_fmed3f(tiv - b.y, -1.f, 1.f);
          s2 += fmaxf(fmaf(-sg, pi - b.x, fabsf(sg)), 0.f); }
        { float sg = __builtin_amdgcn_fmed3f(tiv - b.w, -1.f, 1.f);
          s3 += fmaxf(fmaf(-sg, pi - b.z, fabsf(sg)), 0.f); }
      }
    } else {
      const int jlo = half * 64;
      const int jhi = min(jlo + 64, jcount);
      for (int jj = jlo; jj < jhi; ++jj) {
        float2 a = sj[jj];
        float sg = __builtin_amdgcn_fmed3f(tiv - a.y, -1.f, 1.f);
        s0 += fmaxf(fmaf(-sg, pi - a.x, fabsf(sg)), 0.f);
      }
    }
  }

  float s = (s0 + s1) + (s2 + s3);

  for (int off = 32; off > 0; off >>= 1) {
    s   += __shfl_down(s, off, 64);
    hub += __shfl_down(hub, off, 64);
  }
  __shared__ float red[4][2];
  if ((tid & 63) == 0) {
    int w = tid >> 6;
    red[w][0] = s; red[w][1] = hub;
  }
  __syncthreads();
  if (tid == 0) {
    float scale = (ti == tj) ? 0.5f : 1.0f;
    ws_s[bidx] = ((red[0][0] + red[1][0]) + (red[2][0] + red[3][0])) * scale;
    ws_h[bidx] = (red[0][1] + red[1][1]) + (red[2][1] + red[3][1]);
  }
}

__global__ __launch_bounds__(256) void egl_finalize(
    const float* __restrict__ ws_s, const float* __restrict__ ws_h,
    const float* __restrict__ targ, int nb, int n, float* __restrict__ out) {
  double s = 0.0, h = 0.0;
  for (int idx = threadIdx.x; idx < nb; idx += 256) {
    s += (double)ws_s[idx];
    h += (double)ws_h[idx];
  }
  // target histogram via cumulative counts (targets integer-valued in {0..3})
  int c0 = 0, c1 = 0, c2 = 0;
  for (int idx = threadIdx.x; idx < n; idx += 256) {
    float t = targ[idx];
    c0 += (t < 0.5f) ? 1 : 0;
    c1 += (t < 1.5f) ? 1 : 0;
    c2 += (t < 2.5f) ? 1 : 0;
  }
  for (int off = 32; off > 0; off >>= 1) {
    s  += __shfl_down(s, off, 64);
    h  += __shfl_down(h, off, 64);
    c0 += __shfl_down(c0, off, 64);
    c1 += __shfl_down(c1, off, 64);
    c2 += __shfl_down(c2, off, 64);
  }
  __shared__ double sred[4][2];
  __shared__ int    cred[4][3];
  int w = threadIdx.x >> 6;
  if ((threadIdx.x & 63) == 0) {
    sred[w][0] = s; sred[w][1] = h;
    cred[w][0] = c0; cred[w][1] = c1; cred[w][2] = c2;
  }
  __syncthreads();
  if (threadIdx.x == 0) {
    double S = 0.0, H = 0.0;
    long long C0 = 0, C1 = 0, C2 = 0;
    for (int k = 0; k < 4; ++k) {
      S += sred[k][0]; H += sred[k][1];
      C0 += cred[k][0]; C1 += cred[k][1]; C2 += cred[k][2];
    }
    long long H0 = C0, H1 = C1 - C0, H2 = C2 - C1, H3 = (long long)n - C2;
    long long same = H0 * (H0 - 1) + H1 * (H1 - 1) + H2 * (H2 - 1) + H3 * (H3 - 1);
    long long cnt = ((long long)n * (n - 1) - same) / 2;
    double huber = H / (double)n;
    double rank = (cnt > 0) ? (S / (double)cnt) : 0.0;
    out[0] = (float)(0.7 * huber + 0.3 * rank);
  }
}

extern "C" void kernel_launch(void* const* d_in, const int* in_sizes, int n_in,
                              void* d_out, int out_size, void* d_ws, size_t ws_size,
                              hipStream_t stream) {
  const float* pred = (const float*)d_in[0];
  const float* targ = (const float*)d_in[1];
  const int n = in_sizes[0];

  const int nT = (n + TI - 1) / TI;
  const int nb = nT * (nT + 1) / 2;

  float* ws_s = (float*)d_ws;
  float* ws_h = ws_s + nb;

  egl_pair_kernel<<<nb, NTHREADS, 0, stream>>>(pred, targ, n, nT, ws_s, ws_h);
  egl_finalize<<<1, 256, 0, stream>>>(ws_s, ws_h, targ, nb, n, (float*)d_out);
}